// Round 7
// baseline (277.874 us; speedup 1.0000x reference)
//
#include <hip/hip_runtime.h>
#include <math.h>

// PathFusionEmbedding: B=512, T=100, L=256, D=128, DEPTH=8 (P=9).
// Tree-structured LSTM: one step per tree node (heap indexing, parent = m>>1).
// Split-bf16 MFMA everywhere (h*W = hh*Wh + hh*Wl + hl*Wh; x*W single-term
// bf16 -> fp32-grade accuracy).
// R7: levels 0..6 fused into ONE kernel (one block per tree; trees are
// independent, so only __syncthreads between levels). d=7, d=8 keep the R6
// 512-thread/8-wave kernel. 5 dispatches total (was 11) — inter-dispatch
// boundary cost (~8 us each) had become the dominant term.

#define B_N 512
#define T_N 100
#define L_N 256
#define D_N 128
#define NPT 511

typedef __attribute__((ext_vector_type(8))) short short8;
typedef __attribute__((ext_vector_type(4))) float f32x4;
typedef __attribute__((ext_vector_type(4))) unsigned short ushort4v;

__device__ __forceinline__ unsigned short f2bf(float f) {
    unsigned u = __float_as_uint(f);
    return (unsigned short)((u + 0x7FFFu + ((u >> 16) & 1u)) >> 16);
}
__device__ __forceinline__ float bf2f(unsigned short b) {
    return __uint_as_float(((unsigned)b) << 16);
}
__device__ __forceinline__ float fsigmoid(float x) {
    return __builtin_amdgcn_rcpf(1.f + __builtin_amdgcn_exp2f(-1.44269504f * x));
}
__device__ __forceinline__ float ftanh(float x) {
    return 1.f - 2.f * __builtin_amdgcn_rcpf(1.f + __builtin_amdgcn_exp2f(2.88539009f * x));
}

// ---------------- weight pack + bias prep ----------------
// W'[n'][k] = k<128 ? w_ih[n'][k] : w_hh[n'][k-128]   (n' = gate*128 + j)
// B-fragment order: kb=k>>5, krel=k&31, quad=krel>>3, e=krel&7, tn=n'>>4,
// lane=quad*16+(n'&15); Bhi[((kb*32+tn)*64+lane)*8+e]. Blo for k>=128 only.
__global__ __launch_bounds__(256) void pack_kernel(const float* __restrict__ w_ih,
                                                   const float* __restrict__ w_hh,
                                                   const float* __restrict__ b_ih,
                                                   const float* __restrict__ b_hh,
                                                   unsigned short* __restrict__ Bhi,
                                                   unsigned short* __restrict__ Blo,
                                                   float* __restrict__ bias) {
    const int idx = blockIdx.x * 256 + threadIdx.x;   // 131072 = 512 n' x 256 k
    const int k  = idx & 255;
    const int np = idx >> 8;
    const float val = (k < 128) ? w_ih[(size_t)np * 128 + k]
                                : w_hh[(size_t)np * 128 + (k - 128)];
    const unsigned short hi = f2bf(val);
    const int kb = k >> 5, krel = k & 31, quad = krel >> 3, e = krel & 7;
    const int tn = np >> 4, col = np & 15, lane = quad * 16 + col;
    Bhi[(((size_t)kb * 32 + tn) * 64 + lane) * 8 + e] = hi;
    if (kb >= 4) {
        const unsigned short lo = f2bf(val - bf2f(hi));
        Blo[((((size_t)kb - 4) * 32 + tn) * 64 + lane) * 8 + e] = lo;
    }
    if (k == 0) bias[np] = b_ih[np] + b_hh[np];
}

// ---------------- fused levels 0..6: one block per tree ----------------
// 512 threads = 8 waves. Per level: stage A (64-row tile, rows clamped to
// 2^d), K-loop (MT=4, B double-buffer prefetched from L2), LSTM epilogue to
// global ping-pong h/c. Same-block RAW through L2 is covered by
// __syncthreads' vmcnt drain. Levels are tree-private: no cross-block deps.
__global__ __launch_bounds__(512) void fused_small_kernel(
    const float* __restrict__ node_emb,
    const unsigned short* __restrict__ Bhi,
    const unsigned short* __restrict__ Blo,
    const float* __restrict__ bias,
    float* __restrict__ hA, float* __restrict__ cA,
    float* __restrict__ hB, float* __restrict__ cB)
{
    __shared__ unsigned short AhiF[8 * 4 * 512];   // 32 KB
    __shared__ unsigned short AloF[4 * 4 * 512];   // 16 KB

    const int t    = blockIdx.x;
    const int tid  = threadIdx.x;
    const int idx  = tid >> 6;              // wave 0..7
    const int lane = tid & 63;
    const int ml   = lane & 15;
    const int quad = lane >> 4;
    const int j    = idx * 16 + ml;

    const float bi = bias[j];
    const float bf = bias[128 + j];
    const float bg = bias[256 + j];
    const float bo = bias[384 + j];

    const short8* Bh8 = reinterpret_cast<const short8*>(Bhi);
    const short8* Bl8 = reinterpret_cast<const short8*>(Blo);
    const short8* Ah8 = reinterpret_cast<const short8*>(AhiF);
    const short8* Al8 = reinterpret_cast<const short8*>(AloF);

    for (int d = 0; d <= 6; ++d) {
        const int Mrows = 1 << d;
        const bool root = (d == 0);
        float* hc = (d & 1) ? hB : hA;
        float* cc = (d & 1) ? cB : cA;
        const float* hpv = (d & 1) ? hA : hB;
        const float* cpv = (d & 1) ? cA : cB;
        const int prow = root ? 0 : (t << (d - 1));   // prev-level row base

        // ---- stage A: r = tid>>3 (row 0..63), q = tid&7 (kb) ----
        {
            const int r = tid >> 3;
            const int q = tid & 7;
            int p = r; if (p > Mrows - 1) p = Mrows - 1;
            const int local = Mrows - 1 + p;
            const float* xrow = node_emb + (size_t)(t * NPT + local) * D_N;
            const float* hrow = root ? xrow : (hpv + (size_t)(prow + (p >> 1)) * D_N);
            const int mt = r >> 4, mlr = r & 15;
            const float4 z4 = make_float4(0.f, 0.f, 0.f, 0.f);
            #pragma unroll
            for (int i = 0; i < 8; ++i) {
                const int k  = q * 32 + i * 4;
                const int kb = k >> 5;                // == q
                const int qk = (k & 31) >> 3;
                const int e0 = k & 4;
                float4 v;
                if (k < 128)   v = reinterpret_cast<const float4*>(xrow)[k >> 2];
                else if (root) v = z4;
                else           v = reinterpret_cast<const float4*>(hrow)[(k - 128) >> 2];
                const ushort4v hv = { f2bf(v.x), f2bf(v.y), f2bf(v.z), f2bf(v.w) };
                *reinterpret_cast<ushort4v*>(
                    &AhiF[((kb * 4 + mt) * 64 + qk * 16 + mlr) * 8 + e0]) = hv;
                if (k >= 128) {
                    const ushort4v lv = { f2bf(v.x - bf2f(hv.x)), f2bf(v.y - bf2f(hv.y)),
                                          f2bf(v.z - bf2f(hv.z)), f2bf(v.w - bf2f(hv.w)) };
                    *reinterpret_cast<ushort4v*>(
                        &AloF[(((kb - 4) * 4 + mt) * 64 + qk * 16 + mlr) * 8 + e0]) = lv;
                }
            }
        }
        __syncthreads();

        // ---- prefetch c_prev ----
        float cpre[4][4];
        #pragma unroll
        for (int mt = 0; mt < 4; ++mt)
            #pragma unroll
            for (int r = 0; r < 4; ++r) {
                int m = mt * 16 + quad * 4 + r;
                if (m > Mrows - 1) m = Mrows - 1;
                cpre[mt][r] = root ? 0.f : cpv[(size_t)(prow + (m >> 1)) * D_N + j];
            }

        f32x4 acc[4][4];                     // [mt][gate]
        #pragma unroll
        for (int mt = 0; mt < 4; ++mt)
            #pragma unroll
            for (int g = 0; g < 4; ++g) acc[mt][g] = (f32x4)0.f;

        short8 bh[4], bl[4];
        #pragma unroll
        for (int g = 0; g < 4; ++g)
            bh[g] = Bh8[(0 * 32 + g * 8 + idx) * 64 + lane];

        #pragma unroll
        for (int kb = 0; kb < 8; ++kb) {
            short8 bhn[4], bln[4];
            if (kb < 7) {
                #pragma unroll
                for (int g = 0; g < 4; ++g)
                    bhn[g] = Bh8[((kb + 1) * 32 + g * 8 + idx) * 64 + lane];
                if (kb + 1 >= 4) {
                    #pragma unroll
                    for (int g = 0; g < 4; ++g)
                        bln[g] = Bl8[((kb + 1 - 4) * 32 + g * 8 + idx) * 64 + lane];
                }
            }
            short8 ah[4], al[4];
            #pragma unroll
            for (int mt = 0; mt < 4; ++mt)
                ah[mt] = Ah8[(kb * 4 + mt) * 64 + lane];
            if (kb >= 4) {
                #pragma unroll
                for (int mt = 0; mt < 4; ++mt)
                    al[mt] = Al8[((kb - 4) * 4 + mt) * 64 + lane];
            }
            #pragma unroll
            for (int g = 0; g < 4; ++g) {
                #pragma unroll
                for (int mt = 0; mt < 4; ++mt) {
                    acc[mt][g] = __builtin_amdgcn_mfma_f32_16x16x32_bf16(
                        ah[mt], bh[g], acc[mt][g], 0, 0, 0);
                    if (kb >= 4) {
                        acc[mt][g] = __builtin_amdgcn_mfma_f32_16x16x32_bf16(
                            ah[mt], bl[g], acc[mt][g], 0, 0, 0);
                        acc[mt][g] = __builtin_amdgcn_mfma_f32_16x16x32_bf16(
                            al[mt], bh[g], acc[mt][g], 0, 0, 0);
                    }
                }
            }
            if (kb < 7) {
                #pragma unroll
                for (int g = 0; g < 4; ++g) {
                    bh[g] = bhn[g];
                    if (kb + 1 >= 4) bl[g] = bln[g];
                }
            }
        }

        // ---- epilogue ----
        #pragma unroll
        for (int mt = 0; mt < 4; ++mt) {
            #pragma unroll
            for (int r = 0; r < 4; ++r) {
                const int m = mt * 16 + quad * 4 + r;
                if (m < Mrows) {
                    const float ig = fsigmoid(acc[mt][0][r] + bi);
                    const float fg = fsigmoid(acc[mt][1][r] + bf);
                    const float gv = ftanh(acc[mt][2][r] + bg);
                    const float og = fsigmoid(acc[mt][3][r] + bo);
                    const float cn = fg * cpre[mt][r] + ig * gv;
                    const float hn = og * ftanh(cn);
                    const size_t row = (size_t)((t << d) + m) * D_N + j;
                    cc[row] = cn;
                    hc[row] = hn;
                }
            }
        }
        __syncthreads();   // h/c stores drained (vmcnt) before next staging reads
    }
}

// ---------------- MFMA level kernel (d=7,8) ----------------
// Block: 512 threads = 8 waves; tile = NB=MT*16 nodes x all 512 gates.
// A staged fragment-major in LDS (conflict-free ds_read_b128), B double-buffer
// prefetched from L2, c_prev register-prefetched. store_c=0 skips c output.
template<int MT>
__global__ __launch_bounds__(512, 2) void mfma_level_kernel(
    const float* __restrict__ node_emb,
    const unsigned short* __restrict__ Bhi,
    const unsigned short* __restrict__ Blo,
    const float* __restrict__ bias,
    const float* __restrict__ h_prev,
    const float* __restrict__ c_prev,
    float* __restrict__ h_cur,
    float* __restrict__ c_cur,
    const int d, const int M, const int store_c)
{
    constexpr int NB = MT * 16;
    __shared__ unsigned short AhiF[8 * MT * 512];
    __shared__ unsigned short AloF[4 * MT * 512];

    const int tid = threadIdx.x;
    const int m0  = blockIdx.x * NB;

    // ---- stage A ----
    {
        constexpr int tpr = 512 / NB;
        constexpr int nf  = 256 / tpr;
        const int r = tid / tpr;
        const int q = tid % tpr;
        int gm = m0 + r;
        if (gm > M - 1) gm = M - 1;
        const int mt = r >> 4, mlr = r & 15;
        const int t     = gm >> d;
        const int p     = gm - (t << d);
        const int local = (1 << d) - 1 + p;
        const float* xrow = node_emb + (size_t)(t * NPT + local) * D_N;
        const float* hrow = h_prev + (size_t)(gm >> 1) * D_N;
        #pragma unroll
        for (int i = 0; i < nf / 4; ++i) {
            const int k  = q * nf + i * 4;
            const int kb = k >> 5;
            const int qk = (k & 31) >> 3;
            const int e0 = k & 4;
            const float4 v = (k < 128)
                ? reinterpret_cast<const float4*>(xrow)[k >> 2]
                : reinterpret_cast<const float4*>(hrow)[(k - 128) >> 2];
            const ushort4v hv = { f2bf(v.x), f2bf(v.y), f2bf(v.z), f2bf(v.w) };
            *reinterpret_cast<ushort4v*>(
                &AhiF[((kb * MT + mt) * 64 + qk * 16 + mlr) * 8 + e0]) = hv;
            if (k >= 128) {
                const ushort4v lv = { f2bf(v.x - bf2f(hv.x)), f2bf(v.y - bf2f(hv.y)),
                                      f2bf(v.z - bf2f(hv.z)), f2bf(v.w - bf2f(hv.w)) };
                *reinterpret_cast<ushort4v*>(
                    &AloF[(((kb - 4) * MT + mt) * 64 + qk * 16 + mlr) * 8 + e0]) = lv;
            }
        }
    }
    __syncthreads();

    const int idx  = tid >> 6;
    const int lane = tid & 63;
    const int ml   = lane & 15;
    const int quad = lane >> 4;
    const int j    = idx * 16 + ml;

    float cpre[MT][4];
    #pragma unroll
    for (int mt = 0; mt < MT; ++mt)
        #pragma unroll
        for (int r = 0; r < 4; ++r) {
            int m = m0 + mt * 16 + quad * 4 + r;
            if (m > M - 1) m = M - 1;
            cpre[mt][r] = c_prev[(size_t)(m >> 1) * D_N + j];
        }

    f32x4 acc[MT][4];
    #pragma unroll
    for (int mt = 0; mt < MT; ++mt)
        #pragma unroll
        for (int g = 0; g < 4; ++g) acc[mt][g] = (f32x4)0.f;

    const short8* Bh8 = reinterpret_cast<const short8*>(Bhi);
    const short8* Bl8 = reinterpret_cast<const short8*>(Blo);
    const short8* Ah8 = reinterpret_cast<const short8*>(AhiF);
    const short8* Al8 = reinterpret_cast<const short8*>(AloF);

    short8 bh[4], bl[4];
    #pragma unroll
    for (int g = 0; g < 4; ++g)
        bh[g] = Bh8[(0 * 32 + g * 8 + idx) * 64 + lane];

    #pragma unroll
    for (int kb = 0; kb < 8; ++kb) {
        short8 bhn[4], bln[4];
        if (kb < 7) {
            #pragma unroll
            for (int g = 0; g < 4; ++g)
                bhn[g] = Bh8[((kb + 1) * 32 + g * 8 + idx) * 64 + lane];
            if (kb + 1 >= 4) {
                #pragma unroll
                for (int g = 0; g < 4; ++g)
                    bln[g] = Bl8[((kb + 1 - 4) * 32 + g * 8 + idx) * 64 + lane];
            }
        }
        short8 ah[MT], al[MT];
        #pragma unroll
        for (int mt = 0; mt < MT; ++mt)
            ah[mt] = Ah8[(kb * MT + mt) * 64 + lane];
        if (kb >= 4) {
            #pragma unroll
            for (int mt = 0; mt < MT; ++mt)
                al[mt] = Al8[((kb - 4) * MT + mt) * 64 + lane];
        }
        #pragma unroll
        for (int g = 0; g < 4; ++g) {
            #pragma unroll
            for (int mt = 0; mt < MT; ++mt) {
                acc[mt][g] = __builtin_amdgcn_mfma_f32_16x16x32_bf16(
                    ah[mt], bh[g], acc[mt][g], 0, 0, 0);
                if (kb >= 4) {
                    acc[mt][g] = __builtin_amdgcn_mfma_f32_16x16x32_bf16(
                        ah[mt], bl[g], acc[mt][g], 0, 0, 0);
                    acc[mt][g] = __builtin_amdgcn_mfma_f32_16x16x32_bf16(
                        al[mt], bh[g], acc[mt][g], 0, 0, 0);
                }
            }
        }
        if (kb < 7) {
            #pragma unroll
            for (int g = 0; g < 4; ++g) {
                bh[g] = bhn[g];
                if (kb + 1 >= 4) bl[g] = bln[g];
            }
        }
    }

    const float bi = bias[j];
    const float bf = bias[128 + j];
    const float bg = bias[256 + j];
    const float bo = bias[384 + j];
    #pragma unroll
    for (int mt = 0; mt < MT; ++mt) {
        #pragma unroll
        for (int r = 0; r < 4; ++r) {
            const int m = m0 + mt * 16 + quad * 4 + r;
            if (m < M) {
                const float ig = fsigmoid(acc[mt][0][r] + bi);
                const float fg = fsigmoid(acc[mt][1][r] + bf);
                const float gv = ftanh(acc[mt][2][r] + bg);
                const float og = fsigmoid(acc[mt][3][r] + bo);
                const float cn = fg * cpre[mt][r] + ig * gv;
                const float hn = og * ftanh(cn);
                if (store_c) c_cur[(size_t)m * D_N + j] = cn;
                h_cur[(size_t)m * D_N + j] = hn;
            }
        }
    }
}

// ---------------- fused leaf-extract + gather ----------------
// One 64-lane wave per (b,t) row: ballot over the one-hot cross row -> leaf,
// then out[b,t,:] = active ? h8[t*256+leaf, :] : 0   (2 floats per lane).
__global__ __launch_bounds__(256) void gather_kernel(const float* __restrict__ cross,
                                                     const float* __restrict__ h8,
                                                     float* __restrict__ out) {
    const int bt   = blockIdx.x * 4 + (threadIdx.x >> 6);
    const int lane = threadIdx.x & 63;
    const int t    = bt % T_N;
    const float4 v = reinterpret_cast<const float4*>(cross + (size_t)bt * L_N)[lane];
    int idx = -1;
    if      (v.x > 0.f) idx = lane * 4 + 0;
    else if (v.y > 0.f) idx = lane * 4 + 1;
    else if (v.z > 0.f) idx = lane * 4 + 2;
    else if (v.w > 0.f) idx = lane * 4 + 3;
    const unsigned long long m = __ballot(idx >= 0);
    int lf = -1;
    if (m != 0ULL) {
        const int first = __builtin_ctzll(m);
        lf = __shfl(idx, first);
    }
    float2 o = make_float2(0.f, 0.f);
    if (lf >= 0)
        o = reinterpret_cast<const float2*>(h8 + (size_t)(t * L_N + lf) * D_N)[lane];
    reinterpret_cast<float2*>(out + (size_t)bt * D_N)[lane] = o;
}

extern "C" void kernel_launch(void* const* d_in, const int* in_sizes, int n_in,
                              void* d_out, int out_size, void* d_ws, size_t ws_size,
                              hipStream_t stream) {
    const float* cross    = (const float*)d_in[0];
    const float* node_emb = (const float*)d_in[1];
    const float* w_ih     = (const float*)d_in[2];
    const float* w_hh     = (const float*)d_in[3];
    const float* b_ih     = (const float*)d_in[4];
    const float* b_hh     = (const float*)d_in[5];
    float* out = (float*)d_out;
    float* ws  = (float*)d_ws;

    // ws layout (floats): hA/cA (even levels, <=25600 rows),
    // hB/cB (odd levels, <=12800 rows), bias, Bhi, Blo
    const size_t SA = (size_t)25600 * D_N;
    const size_t SB = (size_t)12800 * D_N;
    float* hA = ws;
    float* cA = hA + SA;
    float* hB = cA + SA;
    float* cB = hB + SB;
    float* bias = cB + SB;
    unsigned short* Bhi = (unsigned short*)(bias + 512);
    unsigned short* Blo = Bhi + 131072;

    pack_kernel<<<512, 256, 0, stream>>>(w_ih, w_hh, b_ih, b_hh, Bhi, Blo, bias);

    // levels 0..6 fused, one block per tree (d=6 output -> hA/cA)
    fused_small_kernel<<<T_N, 512, 0, stream>>>(node_emb, Bhi, Blo, bias,
                                                hA, cA, hB, cB);

    // d=7: hA/cA -> hB/cB ; d=8: hB/cB -> hA (no c store)
    {
        const int M7 = T_N << 7;
        mfma_level_kernel<2><<<M7 / 32, 512, 0, stream>>>(node_emb, Bhi, Blo, bias,
                                                          hA, cA, hB, cB, 7, M7, 1);
        const int M8 = T_N << 8;
        mfma_level_kernel<2><<<M8 / 32, 512, 0, stream>>>(node_emb, Bhi, Blo, bias,
                                                          hB, cB, hA, cA, 8, M8, 0);
    }
    // d=8 wrote hA; fused leaf+gather
    gather_kernel<<<(B_N * T_N) / 4, 256, 0, stream>>>(cross, hA, out);
}

// Round 8
// 200.915 us; speedup vs baseline: 1.3830x; 1.3830x over previous
//
#include <hip/hip_runtime.h>
#include <math.h>

// PathFusionEmbedding: B=512, T=100, L=256, D=128, DEPTH=8 (P=9).
// Tree-structured LSTM: one step per tree node (heap indexing, parent = m>>1).
// Split-bf16 MFMA everywhere (h*W = hh*Wh + hh*Wl + hl*Wh; x*W single-term
// bf16 -> fp32-grade accuracy).
// R8: levels 0..6 via subtree-parallel fused kernel: block=(tree, subtree s of
// 4), 400 blocks; per-wave B fragments REGISTER-RESIDENT across all 7 levels
// (192 VGPR, __launch_bounds__(512,2) -> 256 budget) so the level loop has no
// global B traffic (R7's 123us was B-reload latency at 1 block/CU);
// h/c state in LDS (stride 132). d7/d8 keep proven R6 kernel.

#define B_N 512
#define T_N 100
#define L_N 256
#define D_N 128
#define NPT 511

typedef __attribute__((ext_vector_type(8))) short short8;
typedef __attribute__((ext_vector_type(4))) float f32x4;
typedef __attribute__((ext_vector_type(4))) unsigned short ushort4v;

__device__ __forceinline__ unsigned short f2bf(float f) {
    unsigned u = __float_as_uint(f);
    return (unsigned short)((u + 0x7FFFu + ((u >> 16) & 1u)) >> 16);
}
__device__ __forceinline__ float bf2f(unsigned short b) {
    return __uint_as_float(((unsigned)b) << 16);
}
__device__ __forceinline__ float fsigmoid(float x) {
    return __builtin_amdgcn_rcpf(1.f + __builtin_amdgcn_exp2f(-1.44269504f * x));
}
__device__ __forceinline__ float ftanh(float x) {
    return 1.f - 2.f * __builtin_amdgcn_rcpf(1.f + __builtin_amdgcn_exp2f(2.88539009f * x));
}

// ---------------- weight pack + bias prep ----------------
// W'[n'][k] = k<128 ? w_ih[n'][k] : w_hh[n'][k-128]   (n' = gate*128 + j)
// B-fragment order: kb=k>>5, krel=k&31, quad=krel>>3, e=krel&7, tn=n'>>4,
// lane=quad*16+(n'&15); Bhi[((kb*32+tn)*64+lane)*8+e]. Blo for k>=128 only.
__global__ __launch_bounds__(256) void pack_kernel(const float* __restrict__ w_ih,
                                                   const float* __restrict__ w_hh,
                                                   const float* __restrict__ b_ih,
                                                   const float* __restrict__ b_hh,
                                                   unsigned short* __restrict__ Bhi,
                                                   unsigned short* __restrict__ Blo,
                                                   float* __restrict__ bias) {
    const int idx = blockIdx.x * 256 + threadIdx.x;   // 131072 = 512 n' x 256 k
    const int k  = idx & 255;
    const int np = idx >> 8;
    const float val = (k < 128) ? w_ih[(size_t)np * 128 + k]
                                : w_hh[(size_t)np * 128 + (k - 128)];
    const unsigned short hi = f2bf(val);
    const int kb = k >> 5, krel = k & 31, quad = krel >> 3, e = krel & 7;
    const int tn = np >> 4, col = np & 15, lane = quad * 16 + col;
    Bhi[(((size_t)kb * 32 + tn) * 64 + lane) * 8 + e] = hi;
    if (kb >= 4) {
        const unsigned short lo = f2bf(val - bf2f(hi));
        Blo[((((size_t)kb - 4) * 32 + tn) * 64 + lane) * 8 + e] = lo;
    }
    if (k == 0) bias[np] = b_ih[np] + b_hh[np];
}

// ---------------- subtree-parallel levels 0..6 ----------------
// Block = (tree t, subtree s in 0..3), 512 threads = 8 waves. Per level d:
// rows = 1 (d=0), 2 (d=1), 2^(d-2) (d>=2, p = s*2^(d-2)+r). Levels 0..2 are
// computed redundantly by all 4 subtree blocks (cheap). Parent of local row r
// is local row r>>1 in the previous level buffer (d==2: s>>1). h/c in LDS.
// Per-wave B (4 tn columns x 8 kb hi + 4 kb lo = 48 frags) register-resident
// across the whole kernel. MT=1: one 16-row tile.
__global__ __launch_bounds__(512, 2) void subtree_small_kernel(
    const float* __restrict__ node_emb,
    const unsigned short* __restrict__ Bhi,
    const unsigned short* __restrict__ Blo,
    const float* __restrict__ bias,
    float* __restrict__ h6, float* __restrict__ c6)
{
    __shared__ float hbuf[2][16][132];            // +4 pad: bank-derotated
    __shared__ float cbuf[2][16][132];
    __shared__ unsigned short AhiF[8 * 512];      // [kb][lane*8+e]
    __shared__ unsigned short AloF[4 * 512];

    const int t    = blockIdx.x >> 2;
    const int s    = blockIdx.x & 3;
    const int tid  = threadIdx.x;
    const int idx  = tid >> 6;                    // wave 0..7
    const int lane = tid & 63;
    const int ml   = lane & 15;
    const int quad = lane >> 4;
    const int j    = idx * 16 + ml;

    const float bi = bias[j];
    const float bf = bias[128 + j];
    const float bg = bias[256 + j];
    const float bo = bias[384 + j];

    const short8* Bh8 = reinterpret_cast<const short8*>(Bhi);
    const short8* Bl8 = reinterpret_cast<const short8*>(Blo);
    const short8* Ah8 = reinterpret_cast<const short8*>(AhiF);
    const short8* Al8 = reinterpret_cast<const short8*>(AloF);

    // ---- load B resident: 48 frags = 192 VGPR, reused for all 7 levels ----
    short8 bhR[8][4], blR[4][4];
    #pragma unroll
    for (int kb = 0; kb < 8; ++kb)
        #pragma unroll
        for (int g = 0; g < 4; ++g)
            bhR[kb][g] = Bh8[(kb * 32 + g * 8 + idx) * 64 + lane];
    #pragma unroll
    for (int kb = 0; kb < 4; ++kb)
        #pragma unroll
        for (int g = 0; g < 4; ++g)
            blR[kb][g] = Bl8[(kb * 32 + g * 8 + idx) * 64 + lane];

    for (int d = 0; d <= 6; ++d) {
        const int Mrows = (d == 0) ? 1 : (d == 1) ? 2 : (1 << (d - 2));
        const int pbase = (d >= 2) ? (s << (d - 2)) : 0;
        const bool root = (d == 0);
        const int cur = d & 1, prv = cur ^ 1;

        // ---- stage A tile: r = tid&15 (row), k4 = (tid>>4) and +32 ----
        #pragma unroll
        for (int h2 = 0; h2 < 2; ++h2) {
            const int r  = tid & 15;
            const int k4 = (tid >> 4) + h2 * 32;  // 0..63
            const int k  = k4 * 4;
            int p = r; if (p > Mrows - 1) p = Mrows - 1;
            float4 v;
            if (k < 128) {
                const int local = (1 << d) - 1 + pbase + p;
                v = *reinterpret_cast<const float4*>(
                        node_emb + (size_t)(t * NPT + local) * D_N + k);
            } else if (root) {
                v = make_float4(0.f, 0.f, 0.f, 0.f);
            } else {
                const int pr = (d == 2) ? (s >> 1) : (p >> 1);
                v = *reinterpret_cast<const float4*>(&hbuf[prv][pr][k - 128]);
            }
            const int kb = k >> 5, qk = (k & 31) >> 3, e0 = k & 4;
            const ushort4v hv = { f2bf(v.x), f2bf(v.y), f2bf(v.z), f2bf(v.w) };
            *reinterpret_cast<ushort4v*>(&AhiF[(kb * 64 + qk * 16 + r) * 8 + e0]) = hv;
            if (k >= 128) {
                const ushort4v lv = { f2bf(v.x - bf2f(hv.x)), f2bf(v.y - bf2f(hv.y)),
                                      f2bf(v.z - bf2f(hv.z)), f2bf(v.w - bf2f(hv.w)) };
                *reinterpret_cast<ushort4v*>(
                    &AloF[((kb - 4) * 64 + qk * 16 + r) * 8 + e0]) = lv;
            }
        }
        __syncthreads();

        // ---- c_prev from LDS ----
        float cpre[4];
        #pragma unroll
        for (int rr = 0; rr < 4; ++rr) {
            int m = quad * 4 + rr;
            if (m > Mrows - 1) m = Mrows - 1;
            const int pr = (d == 2) ? (s >> 1) : (m >> 1);
            cpre[rr] = root ? 0.f : cbuf[prv][pr][j];
        }

        f32x4 acc[4];
        #pragma unroll
        for (int g = 0; g < 4; ++g) acc[g] = (f32x4)0.f;

        // ---- K-loop: A from LDS, B from resident registers ----
        #pragma unroll
        for (int kb = 0; kb < 8; ++kb) {
            const short8 ah = Ah8[kb * 64 + lane];
            short8 al;
            if (kb >= 4) al = Al8[(kb - 4) * 64 + lane];
            #pragma unroll
            for (int g = 0; g < 4; ++g) {
                acc[g] = __builtin_amdgcn_mfma_f32_16x16x32_bf16(
                    ah, bhR[kb][g], acc[g], 0, 0, 0);
                if (kb >= 4) {
                    acc[g] = __builtin_amdgcn_mfma_f32_16x16x32_bf16(
                        ah, blR[kb - 4][g], acc[g], 0, 0, 0);
                    acc[g] = __builtin_amdgcn_mfma_f32_16x16x32_bf16(
                        al, bhR[kb][g], acc[g], 0, 0, 0);
                }
            }
        }

        // ---- epilogue: C/D row = quad*4+rr -> node row m, col = ml -> j ----
        #pragma unroll
        for (int rr = 0; rr < 4; ++rr) {
            const int m = quad * 4 + rr;
            if (m < Mrows) {
                const float ig = fsigmoid(acc[0][rr] + bi);
                const float fg = fsigmoid(acc[1][rr] + bf);
                const float gv = ftanh(acc[2][rr] + bg);
                const float og = fsigmoid(acc[3][rr] + bo);
                const float cn = fg * cpre[rr] + ig * gv;
                const float hn = og * ftanh(cn);
                hbuf[cur][m][j] = hn;
                cbuf[cur][m][j] = cn;
                if (d == 6) {
                    const size_t row = (size_t)(t * 64 + s * 16 + m) * D_N + j;
                    h6[row] = hn;
                    c6[row] = cn;
                }
            }
        }
        __syncthreads();
    }
}

// ---------------- MFMA level kernel (d=7,8) ----------------
// Block: 512 threads = 8 waves; tile = NB=MT*16 nodes x all 512 gates.
// A staged fragment-major in LDS (conflict-free ds_read_b128), B double-buffer
// prefetched from L2, c_prev register-prefetched. store_c=0 skips c output.
template<int MT>
__global__ __launch_bounds__(512, 2) void mfma_level_kernel(
    const float* __restrict__ node_emb,
    const unsigned short* __restrict__ Bhi,
    const unsigned short* __restrict__ Blo,
    const float* __restrict__ bias,
    const float* __restrict__ h_prev,
    const float* __restrict__ c_prev,
    float* __restrict__ h_cur,
    float* __restrict__ c_cur,
    const int d, const int M, const int store_c)
{
    constexpr int NB = MT * 16;
    __shared__ unsigned short AhiF[8 * MT * 512];
    __shared__ unsigned short AloF[4 * MT * 512];

    const int tid = threadIdx.x;
    const int m0  = blockIdx.x * NB;

    // ---- stage A ----
    {
        constexpr int tpr = 512 / NB;
        constexpr int nf  = 256 / tpr;
        const int r = tid / tpr;
        const int q = tid % tpr;
        int gm = m0 + r;
        if (gm > M - 1) gm = M - 1;
        const int mt = r >> 4, mlr = r & 15;
        const int t     = gm >> d;
        const int p     = gm - (t << d);
        const int local = (1 << d) - 1 + p;
        const float* xrow = node_emb + (size_t)(t * NPT + local) * D_N;
        const float* hrow = h_prev + (size_t)(gm >> 1) * D_N;
        #pragma unroll
        for (int i = 0; i < nf / 4; ++i) {
            const int k  = q * nf + i * 4;
            const int kb = k >> 5;
            const int qk = (k & 31) >> 3;
            const int e0 = k & 4;
            const float4 v = (k < 128)
                ? reinterpret_cast<const float4*>(xrow)[k >> 2]
                : reinterpret_cast<const float4*>(hrow)[(k - 128) >> 2];
            const ushort4v hv = { f2bf(v.x), f2bf(v.y), f2bf(v.z), f2bf(v.w) };
            *reinterpret_cast<ushort4v*>(
                &AhiF[((kb * MT + mt) * 64 + qk * 16 + mlr) * 8 + e0]) = hv;
            if (k >= 128) {
                const ushort4v lv = { f2bf(v.x - bf2f(hv.x)), f2bf(v.y - bf2f(hv.y)),
                                      f2bf(v.z - bf2f(hv.z)), f2bf(v.w - bf2f(hv.w)) };
                *reinterpret_cast<ushort4v*>(
                    &AloF[(((kb - 4) * MT + mt) * 64 + qk * 16 + mlr) * 8 + e0]) = lv;
            }
        }
    }
    __syncthreads();

    const int idx  = tid >> 6;
    const int lane = tid & 63;
    const int ml   = lane & 15;
    const int quad = lane >> 4;
    const int j    = idx * 16 + ml;

    float cpre[MT][4];
    #pragma unroll
    for (int mt = 0; mt < MT; ++mt)
        #pragma unroll
        for (int r = 0; r < 4; ++r) {
            int m = m0 + mt * 16 + quad * 4 + r;
            if (m > M - 1) m = M - 1;
            cpre[mt][r] = c_prev[(size_t)(m >> 1) * D_N + j];
        }

    f32x4 acc[MT][4];
    #pragma unroll
    for (int mt = 0; mt < MT; ++mt)
        #pragma unroll
        for (int g = 0; g < 4; ++g) acc[mt][g] = (f32x4)0.f;

    const short8* Bh8 = reinterpret_cast<const short8*>(Bhi);
    const short8* Bl8 = reinterpret_cast<const short8*>(Blo);
    const short8* Ah8 = reinterpret_cast<const short8*>(AhiF);
    const short8* Al8 = reinterpret_cast<const short8*>(AloF);

    short8 bh[4], bl[4];
    #pragma unroll
    for (int g = 0; g < 4; ++g)
        bh[g] = Bh8[(0 * 32 + g * 8 + idx) * 64 + lane];

    #pragma unroll
    for (int kb = 0; kb < 8; ++kb) {
        short8 bhn[4], bln[4];
        if (kb < 7) {
            #pragma unroll
            for (int g = 0; g < 4; ++g)
                bhn[g] = Bh8[((kb + 1) * 32 + g * 8 + idx) * 64 + lane];
            if (kb + 1 >= 4) {
                #pragma unroll
                for (int g = 0; g < 4; ++g)
                    bln[g] = Bl8[((kb + 1 - 4) * 32 + g * 8 + idx) * 64 + lane];
            }
        }
        short8 ah[MT], al[MT];
        #pragma unroll
        for (int mt = 0; mt < MT; ++mt)
            ah[mt] = Ah8[(kb * MT + mt) * 64 + lane];
        if (kb >= 4) {
            #pragma unroll
            for (int mt = 0; mt < MT; ++mt)
                al[mt] = Al8[((kb - 4) * MT + mt) * 64 + lane];
        }
        #pragma unroll
        for (int g = 0; g < 4; ++g) {
            #pragma unroll
            for (int mt = 0; mt < MT; ++mt) {
                acc[mt][g] = __builtin_amdgcn_mfma_f32_16x16x32_bf16(
                    ah[mt], bh[g], acc[mt][g], 0, 0, 0);
                if (kb >= 4) {
                    acc[mt][g] = __builtin_amdgcn_mfma_f32_16x16x32_bf16(
                        ah[mt], bl[g], acc[mt][g], 0, 0, 0);
                    acc[mt][g] = __builtin_amdgcn_mfma_f32_16x16x32_bf16(
                        al[mt], bh[g], acc[mt][g], 0, 0, 0);
                }
            }
        }
        if (kb < 7) {
            #pragma unroll
            for (int g = 0; g < 4; ++g) {
                bh[g] = bhn[g];
                if (kb + 1 >= 4) bl[g] = bln[g];
            }
        }
    }

    const float bi = bias[j];
    const float bf = bias[128 + j];
    const float bg = bias[256 + j];
    const float bo = bias[384 + j];
    #pragma unroll
    for (int mt = 0; mt < MT; ++mt) {
        #pragma unroll
        for (int r = 0; r < 4; ++r) {
            const int m = m0 + mt * 16 + quad * 4 + r;
            if (m < M) {
                const float ig = fsigmoid(acc[mt][0][r] + bi);
                const float fg = fsigmoid(acc[mt][1][r] + bf);
                const float gv = ftanh(acc[mt][2][r] + bg);
                const float og = fsigmoid(acc[mt][3][r] + bo);
                const float cn = fg * cpre[mt][r] + ig * gv;
                const float hn = og * ftanh(cn);
                if (store_c) c_cur[(size_t)m * D_N + j] = cn;
                h_cur[(size_t)m * D_N + j] = hn;
            }
        }
    }
}

// ---------------- fused leaf-extract + gather ----------------
// One 64-lane wave per (b,t) row: ballot over the one-hot cross row -> leaf,
// then out[b,t,:] = active ? h8[t*256+leaf, :] : 0   (2 floats per lane).
__global__ __launch_bounds__(256) void gather_kernel(const float* __restrict__ cross,
                                                     const float* __restrict__ h8,
                                                     float* __restrict__ out) {
    const int bt   = blockIdx.x * 4 + (threadIdx.x >> 6);
    const int lane = threadIdx.x & 63;
    const int t    = bt % T_N;
    const float4 v = reinterpret_cast<const float4*>(cross + (size_t)bt * L_N)[lane];
    int idx = -1;
    if      (v.x > 0.f) idx = lane * 4 + 0;
    else if (v.y > 0.f) idx = lane * 4 + 1;
    else if (v.z > 0.f) idx = lane * 4 + 2;
    else if (v.w > 0.f) idx = lane * 4 + 3;
    const unsigned long long m = __ballot(idx >= 0);
    int lf = -1;
    if (m != 0ULL) {
        const int first = __builtin_ctzll(m);
        lf = __shfl(idx, first);
    }
    float2 o = make_float2(0.f, 0.f);
    if (lf >= 0)
        o = reinterpret_cast<const float2*>(h8 + (size_t)(t * L_N + lf) * D_N)[lane];
    reinterpret_cast<float2*>(out + (size_t)bt * D_N)[lane] = o;
}

extern "C" void kernel_launch(void* const* d_in, const int* in_sizes, int n_in,
                              void* d_out, int out_size, void* d_ws, size_t ws_size,
                              hipStream_t stream) {
    const float* cross    = (const float*)d_in[0];
    const float* node_emb = (const float*)d_in[1];
    const float* w_ih     = (const float*)d_in[2];
    const float* w_hh     = (const float*)d_in[3];
    const float* b_ih     = (const float*)d_in[4];
    const float* b_hh     = (const float*)d_in[5];
    float* out = (float*)d_out;
    float* ws  = (float*)d_ws;

    // ws layout (floats): hA/cA (even levels, <=25600 rows),
    // hB/cB (odd levels, <=12800 rows), bias, Bhi, Blo
    const size_t SA = (size_t)25600 * D_N;
    const size_t SB = (size_t)12800 * D_N;
    float* hA = ws;
    float* cA = hA + SA;
    float* hB = cA + SA;
    float* cB = hB + SB;
    float* bias = cB + SB;
    unsigned short* Bhi = (unsigned short*)(bias + 512);
    unsigned short* Blo = Bhi + 131072;

    pack_kernel<<<512, 256, 0, stream>>>(w_ih, w_hh, b_ih, b_hh, Bhi, Blo, bias);

    // levels 0..6: subtree-parallel fused kernel -> h6/c6 in hA/cA
    subtree_small_kernel<<<4 * T_N, 512, 0, stream>>>(node_emb, Bhi, Blo, bias,
                                                      hA, cA);

    // d=7: hA/cA -> hB/cB ; d=8: hB/cB -> hA (no c store)
    {
        const int M7 = T_N << 7;
        mfma_level_kernel<2><<<M7 / 32, 512, 0, stream>>>(node_emb, Bhi, Blo, bias,
                                                          hA, cA, hB, cB, 7, M7, 1);
        const int M8 = T_N << 8;
        mfma_level_kernel<2><<<M8 / 32, 512, 0, stream>>>(node_emb, Bhi, Blo, bias,
                                                          hB, cB, hA, cA, 8, M8, 0);
    }
    // d=8 wrote hA; fused leaf+gather
    gather_kernel<<<(B_N * T_N) / 4, 256, 0, stream>>>(cross, hA, out);
}

// Round 9
// 191.159 us; speedup vs baseline: 1.4536x; 1.0510x over previous
//
#include <hip/hip_runtime.h>
#include <math.h>

// PathFusionEmbedding: B=512, T=100, L=256, D=128, DEPTH=8 (P=9).
// Tree-structured LSTM: one step per tree node (heap indexing, parent = m>>1).
// Split-bf16 MFMA everywhere (h*W = hh*Wh + hh*Wl + hl*Wh; x*W single-term
// bf16 -> fp32-grade accuracy).
// R9: ENTIRE tree (levels 0..8) in one kernel, block=(tree t, subtree s of 4):
// subtree s owns rows [s*2^(d-2),(s+1)*2^(d-2)) at level d>=2 -> parents are
// always in-block. Per-wave B register-resident (192 VGPR). Levels 0..6: h/c
// in LDS. Level 7: h6/c6 from LDS, h7/c7 -> per-block global scratch (L1-hot,
// same-block RAW after __syncthreads vmcnt drain). Level 8: two 32-row passes,
// h8 -> global. 3 dispatches total: pack -> tree -> gather.

#define B_N 512
#define T_N 100
#define L_N 256
#define D_N 128
#define NPT 511

typedef __attribute__((ext_vector_type(8))) short short8;
typedef __attribute__((ext_vector_type(4))) float f32x4;
typedef __attribute__((ext_vector_type(4))) unsigned short ushort4v;

__device__ __forceinline__ unsigned short f2bf(float f) {
    unsigned u = __float_as_uint(f);
    return (unsigned short)((u + 0x7FFFu + ((u >> 16) & 1u)) >> 16);
}
__device__ __forceinline__ float bf2f(unsigned short b) {
    return __uint_as_float(((unsigned)b) << 16);
}
__device__ __forceinline__ float fsigmoid(float x) {
    return __builtin_amdgcn_rcpf(1.f + __builtin_amdgcn_exp2f(-1.44269504f * x));
}
__device__ __forceinline__ float ftanh(float x) {
    return 1.f - 2.f * __builtin_amdgcn_rcpf(1.f + __builtin_amdgcn_exp2f(2.88539009f * x));
}

// ---------------- weight pack + bias prep ----------------
// W'[n'][k] = k<128 ? w_ih[n'][k] : w_hh[n'][k-128]   (n' = gate*128 + j)
// B-fragment order: kb=k>>5, krel=k&31, quad=krel>>3, e=krel&7, tn=n'>>4,
// lane=quad*16+(n'&15); Bhi[((kb*32+tn)*64+lane)*8+e]. Blo for k>=128 only.
__global__ __launch_bounds__(256) void pack_kernel(const float* __restrict__ w_ih,
                                                   const float* __restrict__ w_hh,
                                                   const float* __restrict__ b_ih,
                                                   const float* __restrict__ b_hh,
                                                   unsigned short* __restrict__ Bhi,
                                                   unsigned short* __restrict__ Blo,
                                                   float* __restrict__ bias) {
    const int idx = blockIdx.x * 256 + threadIdx.x;   // 131072 = 512 n' x 256 k
    const int k  = idx & 255;
    const int np = idx >> 8;
    const float val = (k < 128) ? w_ih[(size_t)np * 128 + k]
                                : w_hh[(size_t)np * 128 + (k - 128)];
    const unsigned short hi = f2bf(val);
    const int kb = k >> 5, krel = k & 31, quad = krel >> 3, e = krel & 7;
    const int tn = np >> 4, col = np & 15, lane = quad * 16 + col;
    Bhi[(((size_t)kb * 32 + tn) * 64 + lane) * 8 + e] = hi;
    if (kb >= 4) {
        const unsigned short lo = f2bf(val - bf2f(hi));
        Blo[((((size_t)kb - 4) * 32 + tn) * 64 + lane) * 8 + e] = lo;
    }
    if (k == 0) bias[np] = b_ih[np] + b_hh[np];
}

// ---------------- whole-tree kernel, levels 0..8 ----------------
// Block = (tree t, subtree s), 512 threads = 8 waves. A-fragment LDS layout
// holds 2 tiles (MT=2): AhiF[((kb*2+mt)*64+lane)*8+e].
__global__ __launch_bounds__(512, 2) void tree_kernel(
    const float* __restrict__ node_emb,
    const unsigned short* __restrict__ Bhi,
    const unsigned short* __restrict__ Blo,
    const float* __restrict__ bias,
    float* __restrict__ h7g, float* __restrict__ c7g,
    float* __restrict__ h8)
{
    __shared__ float hbuf[2][16][132];            // levels 0..6 h (stride 132)
    __shared__ float cbuf[2][16][132];
    __shared__ unsigned short AhiF[8 * 2 * 512];  // 16 KB
    __shared__ unsigned short AloF[4 * 2 * 512];  //  8 KB

    const int t    = blockIdx.x >> 2;
    const int s    = blockIdx.x & 3;
    const int tid  = threadIdx.x;
    const int idx  = tid >> 6;                    // wave 0..7
    const int lane = tid & 63;
    const int ml   = lane & 15;
    const int quad = lane >> 4;
    const int j    = idx * 16 + ml;

    const float bi = bias[j];
    const float bf = bias[128 + j];
    const float bg = bias[256 + j];
    const float bo = bias[384 + j];

    const short8* Bh8 = reinterpret_cast<const short8*>(Bhi);
    const short8* Bl8 = reinterpret_cast<const short8*>(Blo);
    const short8* Ah8 = reinterpret_cast<const short8*>(AhiF);
    const short8* Al8 = reinterpret_cast<const short8*>(AloF);

    // ---- B register-resident for the whole kernel: 48 frags = 192 VGPR ----
    short8 bhR[8][4], blR[4][4];
    #pragma unroll
    for (int kb = 0; kb < 8; ++kb)
        #pragma unroll
        for (int g = 0; g < 4; ++g)
            bhR[kb][g] = Bh8[(kb * 32 + g * 8 + idx) * 64 + lane];
    #pragma unroll
    for (int kb = 0; kb < 4; ++kb)
        #pragma unroll
        for (int g = 0; g < 4; ++g)
            blR[kb][g] = Bl8[(kb * 32 + g * 8 + idx) * 64 + lane];

    // =================== levels 0..6 (h/c in LDS) ===================
    for (int d = 0; d <= 6; ++d) {
        const int Mrows = (d == 0) ? 1 : (d == 1) ? 2 : (1 << (d - 2));
        const int pbase = (d >= 2) ? (s << (d - 2)) : 0;
        const bool root = (d == 0);
        const int cur = d & 1, prv = cur ^ 1;

        // ---- stage A (16 rows, mt=0 slice) ----
        #pragma unroll
        for (int h2 = 0; h2 < 2; ++h2) {
            const int r  = tid & 15;
            const int k4 = (tid >> 4) + h2 * 32;  // 0..63
            const int k  = k4 * 4;
            int p = r; if (p > Mrows - 1) p = Mrows - 1;
            float4 v;
            if (k < 128) {
                const int local = (1 << d) - 1 + pbase + p;
                v = *reinterpret_cast<const float4*>(
                        node_emb + (size_t)(t * NPT + local) * D_N + k);
            } else if (root) {
                v = make_float4(0.f, 0.f, 0.f, 0.f);
            } else {
                const int pr = (d == 2) ? (s >> 1) : (p >> 1);
                v = *reinterpret_cast<const float4*>(&hbuf[prv][pr][k - 128]);
            }
            const int kb = k >> 5, qk = (k & 31) >> 3, e0 = k & 4;
            const ushort4v hv = { f2bf(v.x), f2bf(v.y), f2bf(v.z), f2bf(v.w) };
            *reinterpret_cast<ushort4v*>(
                &AhiF[((kb * 2 + 0) * 64 + qk * 16 + r) * 8 + e0]) = hv;
            if (k >= 128) {
                const ushort4v lv = { f2bf(v.x - bf2f(hv.x)), f2bf(v.y - bf2f(hv.y)),
                                      f2bf(v.z - bf2f(hv.z)), f2bf(v.w - bf2f(hv.w)) };
                *reinterpret_cast<ushort4v*>(
                    &AloF[(((kb - 4) * 2 + 0) * 64 + qk * 16 + r) * 8 + e0]) = lv;
            }
        }
        __syncthreads();

        float cpre[4];
        #pragma unroll
        for (int rr = 0; rr < 4; ++rr) {
            int m = quad * 4 + rr;
            if (m > Mrows - 1) m = Mrows - 1;
            const int pr = (d == 2) ? (s >> 1) : (m >> 1);
            cpre[rr] = root ? 0.f : cbuf[prv][pr][j];
        }

        f32x4 acc[4];
        #pragma unroll
        for (int g = 0; g < 4; ++g) acc[g] = (f32x4)0.f;

        #pragma unroll
        for (int kb = 0; kb < 8; ++kb) {
            const short8 ah = Ah8[(kb * 2 + 0) * 64 + lane];
            short8 al;
            if (kb >= 4) al = Al8[((kb - 4) * 2 + 0) * 64 + lane];
            #pragma unroll
            for (int g = 0; g < 4; ++g) {
                acc[g] = __builtin_amdgcn_mfma_f32_16x16x32_bf16(
                    ah, bhR[kb][g], acc[g], 0, 0, 0);
                if (kb >= 4) {
                    acc[g] = __builtin_amdgcn_mfma_f32_16x16x32_bf16(
                        ah, blR[kb - 4][g], acc[g], 0, 0, 0);
                    acc[g] = __builtin_amdgcn_mfma_f32_16x16x32_bf16(
                        al, bhR[kb][g], acc[g], 0, 0, 0);
                }
            }
        }

        #pragma unroll
        for (int rr = 0; rr < 4; ++rr) {
            const int m = quad * 4 + rr;
            if (m < Mrows) {
                const float ig = fsigmoid(acc[0][rr] + bi);
                const float fg = fsigmoid(acc[1][rr] + bf);
                const float gv = ftanh(acc[2][rr] + bg);
                const float og = fsigmoid(acc[3][rr] + bo);
                const float cn = fg * cpre[rr] + ig * gv;
                const float hn = og * ftanh(cn);
                hbuf[cur][m][j] = hn;
                cbuf[cur][m][j] = cn;
            }
        }
        __syncthreads();
    }

    // =================== level 7 (32 rows, 2 tiles) ===================
    {
        #pragma unroll
        for (int h2 = 0; h2 < 4; ++h2) {
            const int r  = tid & 31;
            const int k4 = (tid >> 5) + h2 * 16;  // 0..63
            const int k  = k4 * 4;
            const int mt = r >> 4, mlr = r & 15;
            float4 v;
            if (k < 128) {
                const int local = 127 + s * 32 + r;
                v = *reinterpret_cast<const float4*>(
                        node_emb + (size_t)(t * NPT + local) * D_N + k);
            } else {
                v = *reinterpret_cast<const float4*>(&hbuf[0][r >> 1][k - 128]);
            }
            const int kb = k >> 5, qk = (k & 31) >> 3, e0 = k & 4;
            const ushort4v hv = { f2bf(v.x), f2bf(v.y), f2bf(v.z), f2bf(v.w) };
            *reinterpret_cast<ushort4v*>(
                &AhiF[((kb * 2 + mt) * 64 + qk * 16 + mlr) * 8 + e0]) = hv;
            if (k >= 128) {
                const ushort4v lv = { f2bf(v.x - bf2f(hv.x)), f2bf(v.y - bf2f(hv.y)),
                                      f2bf(v.z - bf2f(hv.z)), f2bf(v.w - bf2f(hv.w)) };
                *reinterpret_cast<ushort4v*>(
                    &AloF[(((kb - 4) * 2 + mt) * 64 + qk * 16 + mlr) * 8 + e0]) = lv;
            }
        }
        __syncthreads();

        #pragma unroll
        for (int mt = 0; mt < 2; ++mt) {
            float cpre[4];
            #pragma unroll
            for (int rr = 0; rr < 4; ++rr) {
                const int m = mt * 16 + quad * 4 + rr;
                cpre[rr] = cbuf[0][m >> 1][j];
            }
            f32x4 acc[4];
            #pragma unroll
            for (int g = 0; g < 4; ++g) acc[g] = (f32x4)0.f;
            #pragma unroll
            for (int kb = 0; kb < 8; ++kb) {
                const short8 ah = Ah8[(kb * 2 + mt) * 64 + lane];
                short8 al;
                if (kb >= 4) al = Al8[((kb - 4) * 2 + mt) * 64 + lane];
                #pragma unroll
                for (int g = 0; g < 4; ++g) {
                    acc[g] = __builtin_amdgcn_mfma_f32_16x16x32_bf16(
                        ah, bhR[kb][g], acc[g], 0, 0, 0);
                    if (kb >= 4) {
                        acc[g] = __builtin_amdgcn_mfma_f32_16x16x32_bf16(
                            ah, blR[kb - 4][g], acc[g], 0, 0, 0);
                        acc[g] = __builtin_amdgcn_mfma_f32_16x16x32_bf16(
                            al, bhR[kb][g], acc[g], 0, 0, 0);
                    }
                }
            }
            #pragma unroll
            for (int rr = 0; rr < 4; ++rr) {
                const int m = mt * 16 + quad * 4 + rr;
                const float ig = fsigmoid(acc[0][rr] + bi);
                const float fg = fsigmoid(acc[1][rr] + bf);
                const float gv = ftanh(acc[2][rr] + bg);
                const float og = fsigmoid(acc[3][rr] + bo);
                const float cn = fg * cpre[rr] + ig * gv;
                const float hn = og * ftanh(cn);
                const size_t row = (size_t)(blockIdx.x * 32 + m) * D_N + j;
                h7g[row] = hn;
                c7g[row] = cn;
            }
        }
        __syncthreads();   // drain h7g/c7g stores before level-8 staging reads
    }

    // =================== level 8 (64 rows, 2 passes of 32) ===================
    for (int pp = 0; pp < 2; ++pp) {
        #pragma unroll
        for (int h2 = 0; h2 < 4; ++h2) {
            const int r  = tid & 31;
            const int m2 = pp * 32 + r;           // subtree-local row 0..63
            const int k4 = (tid >> 5) + h2 * 16;
            const int k  = k4 * 4;
            const int mt = r >> 4, mlr = r & 15;
            float4 v;
            if (k < 128) {
                const int local = 255 + s * 64 + m2;
                v = *reinterpret_cast<const float4*>(
                        node_emb + (size_t)(t * NPT + local) * D_N + k);
            } else {
                v = *reinterpret_cast<const float4*>(
                        h7g + (size_t)(blockIdx.x * 32 + (m2 >> 1)) * D_N + (k - 128));
            }
            const int kb = k >> 5, qk = (k & 31) >> 3, e0 = k & 4;
            const ushort4v hv = { f2bf(v.x), f2bf(v.y), f2bf(v.z), f2bf(v.w) };
            *reinterpret_cast<ushort4v*>(
                &AhiF[((kb * 2 + mt) * 64 + qk * 16 + mlr) * 8 + e0]) = hv;
            if (k >= 128) {
                const ushort4v lv = { f2bf(v.x - bf2f(hv.x)), f2bf(v.y - bf2f(hv.y)),
                                      f2bf(v.z - bf2f(hv.z)), f2bf(v.w - bf2f(hv.w)) };
                *reinterpret_cast<ushort4v*>(
                    &AloF[(((kb - 4) * 2 + mt) * 64 + qk * 16 + mlr) * 8 + e0]) = lv;
            }
        }
        __syncthreads();

        #pragma unroll
        for (int mt = 0; mt < 2; ++mt) {
            float cpre[4];
            #pragma unroll
            for (int rr = 0; rr < 4; ++rr) {
                const int m2 = pp * 32 + mt * 16 + quad * 4 + rr;
                cpre[rr] = c7g[(size_t)(blockIdx.x * 32 + (m2 >> 1)) * D_N + j];
            }
            f32x4 acc[4];
            #pragma unroll
            for (int g = 0; g < 4; ++g) acc[g] = (f32x4)0.f;
            #pragma unroll
            for (int kb = 0; kb < 8; ++kb) {
                const short8 ah = Ah8[(kb * 2 + mt) * 64 + lane];
                short8 al;
                if (kb >= 4) al = Al8[((kb - 4) * 2 + mt) * 64 + lane];
                #pragma unroll
                for (int g = 0; g < 4; ++g) {
                    acc[g] = __builtin_amdgcn_mfma_f32_16x16x32_bf16(
                        ah, bhR[kb][g], acc[g], 0, 0, 0);
                    if (kb >= 4) {
                        acc[g] = __builtin_amdgcn_mfma_f32_16x16x32_bf16(
                            ah, blR[kb - 4][g], acc[g], 0, 0, 0);
                        acc[g] = __builtin_amdgcn_mfma_f32_16x16x32_bf16(
                            al, bhR[kb][g], acc[g], 0, 0, 0);
                    }
                }
            }
            #pragma unroll
            for (int rr = 0; rr < 4; ++rr) {
                const int m2 = pp * 32 + mt * 16 + quad * 4 + rr;
                const float ig = fsigmoid(acc[0][rr] + bi);
                const float fg = fsigmoid(acc[1][rr] + bf);
                const float gv = ftanh(acc[2][rr] + bg);
                const float og = fsigmoid(acc[3][rr] + bo);
                const float cn = fg * cpre[rr] + ig * gv;
                const float hn = og * ftanh(cn);
                h8[(size_t)((t << 8) + s * 64 + m2) * D_N + j] = hn;
            }
        }
        __syncthreads();   // A buffers reused by next pass
    }
}

// ---------------- fused leaf-extract + gather ----------------
// One 64-lane wave per (b,t) row: ballot over the one-hot cross row -> leaf,
// then out[b,t,:] = active ? h8[t*256+leaf, :] : 0   (2 floats per lane).
__global__ __launch_bounds__(256) void gather_kernel(const float* __restrict__ cross,
                                                     const float* __restrict__ h8,
                                                     float* __restrict__ out) {
    const int bt   = blockIdx.x * 4 + (threadIdx.x >> 6);
    const int lane = threadIdx.x & 63;
    const int t    = bt % T_N;
    const float4 v = reinterpret_cast<const float4*>(cross + (size_t)bt * L_N)[lane];
    int idx = -1;
    if      (v.x > 0.f) idx = lane * 4 + 0;
    else if (v.y > 0.f) idx = lane * 4 + 1;
    else if (v.z > 0.f) idx = lane * 4 + 2;
    else if (v.w > 0.f) idx = lane * 4 + 3;
    const unsigned long long m = __ballot(idx >= 0);
    int lf = -1;
    if (m != 0ULL) {
        const int first = __builtin_ctzll(m);
        lf = __shfl(idx, first);
    }
    float2 o = make_float2(0.f, 0.f);
    if (lf >= 0)
        o = reinterpret_cast<const float2*>(h8 + (size_t)(t * L_N + lf) * D_N)[lane];
    reinterpret_cast<float2*>(out + (size_t)bt * D_N)[lane] = o;
}

extern "C" void kernel_launch(void* const* d_in, const int* in_sizes, int n_in,
                              void* d_out, int out_size, void* d_ws, size_t ws_size,
                              hipStream_t stream) {
    const float* cross    = (const float*)d_in[0];
    const float* node_emb = (const float*)d_in[1];
    const float* w_ih     = (const float*)d_in[2];
    const float* w_hh     = (const float*)d_in[3];
    const float* b_ih     = (const float*)d_in[4];
    const float* b_hh     = (const float*)d_in[5];
    float* out = (float*)d_out;
    float* ws  = (float*)d_ws;

    // ws layout (floats): h8[25600*128], h7g[12800*128], c7g[12800*128],
    // bias[512], Bhi[131072 u16], Blo[65536 u16]
    float* h8   = ws;
    float* h7g  = h8 + (size_t)25600 * D_N;
    float* c7g  = h7g + (size_t)12800 * D_N;
    float* bias = c7g + (size_t)12800 * D_N;
    unsigned short* Bhi = (unsigned short*)(bias + 512);
    unsigned short* Blo = Bhi + 131072;

    pack_kernel<<<512, 256, 0, stream>>>(w_ih, w_hh, b_ih, b_hh, Bhi, Blo, bias);

    // whole tree: levels 0..8, one block per (tree, subtree)
    tree_kernel<<<4 * T_N, 512, 0, stream>>>(node_emb, Bhi, Blo, bias,
                                             h7g, c7g, h8);

    // fused leaf+gather
    gather_kernel<<<(B_N * T_N) / 4, 256, 0, stream>>>(cross, h8, out);
}